// Round 2
// baseline (634.271 us; speedup 1.0000x reference)
//
#include <hip/hip_runtime.h>
#include <cstdint>
#include <cmath>

#define IMG_H 128
#define IMG_W 128
#define TILE 16
#define TILES_X (IMG_W / TILE)      // 8
#define TILES_Y (IMG_H / TILE)      // 8
#define NTILES (TILES_X * TILES_Y)  // 64
#define NSUB 8                      // sub-lists per bin (f & 7) -> contention/parallelism split
#define CHUNK_F 64                  // faces staged to LDS per chunk

// PROJ constants: computed in double exactly as the Python reference, then cast to f32.
constexpr double FOCAL_D = 140.0, NEAR_D = 0.1, FAR_D = 10.0;
constexpr double RIGHT_D = (IMG_W - 1.0) / 2.0 * NEAR_D / FOCAL_D;
constexpr double TOP_D   = RIGHT_D * ((double)IMG_H / (double)IMG_W);
constexpr float P00 = (float)(NEAR_D / RIGHT_D);
constexpr float P11 = (float)(NEAR_D / TOP_D);
constexpr float P22 = (float)(-(FAR_D + NEAR_D) / (FAR_D - NEAR_D));
constexpr float P32 = (float)(-2.0 * FAR_D * NEAR_D / (FAR_D - NEAR_D));

__device__ __forceinline__ unsigned long long packKey(float z, int f) {
    unsigned int zb = __float_as_uint(z);
    zb = (zb & 0x80000000u) ? ~zb : (zb | 0x80000000u);  // monotone total order
    return ((unsigned long long)zb << 32) | (unsigned int)f;
}

// ---------------- vertex transform: world -> screen (sx, sy, sz, w) ----------------
__global__ void k_vertex(const float* __restrict__ verts, const float* __restrict__ poses,
                         float4* __restrict__ vscr, int B, int N) {
#pragma clang fp contract(off)
    int id = blockIdx.x * blockDim.x + threadIdx.x;
    if (id >= B * N) return;
    int b = id / N;
    const float* v = verts + (size_t)id * 3;
    const float* P = poses + (size_t)b * 16;
    float x = v[0], y = v[1], z = v[2];
    float cp[4][4] = {
        { P[0],  P[1],  P[2],  P[3]  },
        {-P[4], -P[5], -P[6], -P[7]  },
        {-P[8], -P[9], -P[10],-P[11] },
        { P[12], P[13], P[14], P[15] }
    };
    float cam[4];
    for (int j = 0; j < 4; ++j)
        cam[j] = ((x * cp[j][0] + y * cp[j][1]) + z * cp[j][2]) + cp[j][3];
    float c0 = cam[0] * P00;
    float c1 = cam[1] * P11;
    float c2 = (cam[2] * P22) + (cam[3] * P32);
    float c3 = cam[2] * (-1.0f);
    float sx = ((c0 / c3) * 0.5f + 0.5f) * (float)IMG_W;
    float sy = (0.5f - (c1 / c3) * 0.5f) * (float)IMG_H;
    float sz = c2 / c3;
    vscr[id] = make_float4(sx, sy, sz, c3);
}

// ---------------- phase 1: bin faces into 16x16-px tiles (NSUB sub-lists each) ----------------
__global__ void k_bin(const int* __restrict__ faces, const float4* __restrict__ vscr,
                      float4* __restrict__ rec, int* __restrict__ list, int* __restrict__ cnt,
                      int B, int N, int F) {
#pragma clang fp contract(off)
    int id = blockIdx.x * blockDim.x + threadIdx.x;
    if (id >= B * F) return;
    int b = id / F, f = id - b * F;
    int i0 = faces[f * 3 + 0], i1 = faces[f * 3 + 1], i2 = faces[f * 3 + 2];
    float4 v0 = vscr[(size_t)b * N + i0];
    float4 v1 = vscr[(size_t)b * N + i1];
    float4 v2 = vscr[(size_t)b * N + i2];

    // reference: ok=false if any w <= 1e-6 -> face contributes nothing
    if (!(v0.w > 1e-6f && v1.w > 1e-6f && v2.w > 1e-6f)) return;

    float minx = fminf(v0.x, fminf(v1.x, v2.x));
    float maxx = fmaxf(v0.x, fmaxf(v1.x, v2.x));
    float miny = fminf(v0.y, fminf(v1.y, v2.y));
    float maxy = fmaxf(v0.y, fmaxf(v1.y, v2.y));
    // NaN guard (reference: NaN edge fns -> inside false everywhere)
    if (!(minx <= maxx) || !(miny <= maxy)) return;
    // clamp to sane range before int conversion
    minx = fmaxf(minx, -4.0f);  maxx = fminf(maxx, (float)IMG_W + 4.0f);
    miny = fmaxf(miny, -4.0f);  maxy = fminf(maxy, (float)IMG_H + 4.0f);
    // pixel index range with >=1px guard band for edge-fn rounding slack (verified in prior kernel)
    int xlo = max(0, (int)floorf(minx) - 1);
    int xhi = min(IMG_W - 1, (int)floorf(maxx) + 1);
    int ylo = max(0, (int)floorf(miny) - 1);
    int yhi = min(IMG_H - 1, (int)floorf(maxy) + 1);
    if (xlo > xhi || ylo > yhi) return;

    // packed per-face record for fast phase-2 staging
    size_t r = (size_t)id * 3;
    rec[r] = v0; rec[r + 1] = v1; rec[r + 2] = v2;

    int tx0 = xlo >> 4, tx1 = xhi >> 4, ty0 = ylo >> 4, ty1 = yhi >> 4;
    int sub = f & (NSUB - 1);
    int cap = (F + NSUB - 1) / NSUB;   // faces with f%NSUB==sub per batch <= cap -> no overflow
    for (int ty = ty0; ty <= ty1; ++ty)
        for (int tx = tx0; tx <= tx1; ++tx) {
            int bin = b * NTILES + ty * TILES_X + tx;
            int slot = atomicAdd(&cnt[bin * NSUB + sub], 1);
            list[((size_t)bin * NSUB + sub) * cap + slot] = f;
        }
}

// ---------------- phase 2: one block per (bin, sub-list); register z-buffer, LDS face broadcast ----
__global__ __launch_bounds__(256) void k_rasterBins(const int* __restrict__ list,
        const int* __restrict__ cnt, const float4* __restrict__ rec,
        unsigned long long* __restrict__ keybuf, int B, int F) {
#pragma clang fp contract(off)
    int bin = blockIdx.x >> 3;          // NSUB == 8
    int sub = blockIdx.x & 7;
    int b = bin / NTILES;
    int tile = bin - b * NTILES;
    int n = cnt[bin * NSUB + sub];
    if (n == 0) return;
    int cap = (F + NSUB - 1) / NSUB;
    const int* mylist = list + ((size_t)bin * NSUB + sub) * cap;

    int tx = tile & (TILES_X - 1), ty = tile >> 3;
    int t = threadIdx.x;
    int x = (tx << 4) + (t & 15);
    int y = (ty << 4) + (t >> 4);
    float px = (float)x + 0.5f, py = (float)y + 0.5f;
    // wave-uniform y-strip bounds: each wave covers 4 consecutive rows of the tile
    float strip_py0 = (float)((ty << 4) + ((t >> 4) & ~3)) + 0.5f;
    float strip_py1 = strip_py0 + 3.0f;

    unsigned long long key = ~0ull;

    __shared__ float4 sv0[CHUNK_F], sv1[CHUNK_F], sv2[CHUNK_F];
    __shared__ int sfid[CHUNK_F];

    for (int base = 0; base < n; base += CHUNK_F) {
        int m = min(CHUNK_F, n - base);
        __syncthreads();
        if (t < m) {
            int f = mylist[base + t];
            sfid[t] = f;
            size_t r = ((size_t)b * F + f) * 3;
            sv0[t] = rec[r]; sv1[t] = rec[r + 1]; sv2[t] = rec[r + 2];
        }
        __syncthreads();
        for (int j = 0; j < m; ++j) {
            float4 a = sv0[j], bv = sv1[j], c = sv2[j];
            // conservative wave-level y reject (guard band consistent with binning's +-1 px)
            float fminy = fminf(a.y, fminf(bv.y, c.y));
            float fmaxy = fmaxf(a.y, fmaxf(bv.y, c.y));
            if (fminy - 1.5f > strip_py1 || fmaxy + 1.5f < strip_py0) continue;
            // bit-exact reference op order (contract off)
            float e0 = (c.x - bv.x) * (py - bv.y) - (c.y - bv.y) * (px - bv.x);
            float e1 = (a.x - c.x) * (py - c.y) - (a.y - c.y) * (px - c.x);
            float e2 = (bv.x - a.x) * (py - a.y) - (bv.y - a.y) * (px - a.x);
            float area = (e0 + e1) + e2;
            bool okA = fabsf(area) > 1e-9f;
            float s = (area > 0.0f) ? 1.0f : ((area < 0.0f) ? -1.0f : area);
            bool inside = (e0 * s >= 0.0f) && (e1 * s >= 0.0f) && (e2 * s >= 0.0f) && okA;
            if (__ballot(inside)) {
                float den = okA ? area : 1.0f;
                float zpix = ((e0 * a.z + e1 * bv.z) + e2 * c.z) / den;
                if (inside && (zpix >= -1.0f) && (zpix <= 1.0f)) {
                    unsigned long long k = packKey(zpix, sfid[j]);
                    key = (k < key) ? k : key;    // register z-buffer: no global traffic
                }
            }
        }
    }
    if (key != ~0ull) {
        unsigned long long* ap = &keybuf[(size_t)b * (IMG_H * IMG_W) + (size_t)y * IMG_W + x];
        atomicMin(ap, key);                      // <= NSUB atomics per pixel total
    }
}

// ---------------- fallback rasterizer (prior verified kernel) if workspace too small ----------------
__global__ __launch_bounds__(256) void k_rasterF(const int* __restrict__ faces,
                                                 const float4* __restrict__ vscr,
                                                 unsigned long long* __restrict__ keybuf,
                                                 int B, int N, int F) {
#pragma clang fp contract(off)
    int wid = __builtin_amdgcn_readfirstlane(blockIdx.x * 4 + (threadIdx.x >> 6));
    if (wid >= B * F) return;
    int b = wid / F;
    int f = wid - b * F;
    int lane = threadIdx.x & 63;

    int i0 = faces[f * 3 + 0], i1 = faces[f * 3 + 1], i2 = faces[f * 3 + 2];
    float4 v0 = vscr[(size_t)b * N + i0];
    float4 v1 = vscr[(size_t)b * N + i1];
    float4 v2 = vscr[(size_t)b * N + i2];
    if (!(v0.w > 1e-6f && v1.w > 1e-6f && v2.w > 1e-6f)) return;

    float dx0 = v2.x - v1.x, dy0 = v2.y - v1.y;
    float dx1 = v0.x - v2.x, dy1 = v0.y - v2.y;
    float dx2 = v1.x - v0.x, dy2 = v1.y - v0.y;
    float z0 = v0.z, z1 = v1.z, z2 = v2.z;

    float minx = fminf(v0.x, fminf(v1.x, v2.x));
    float maxx = fmaxf(v0.x, fmaxf(v1.x, v2.x));
    float miny = fminf(v0.y, fminf(v1.y, v2.y));
    float maxy = fmaxf(v0.y, fmaxf(v1.y, v2.y));
    if (!(minx <= maxx) || !(miny <= maxy)) return;
    minx = fmaxf(minx, -4.0f);  maxx = fminf(maxx, (float)IMG_W + 4.0f);
    miny = fmaxf(miny, -4.0f);  maxy = fminf(maxy, (float)IMG_H + 4.0f);
    int xlo = max(0, (int)floorf(minx) - 1);
    int xhi = min(IMG_W - 1, (int)floorf(maxx) + 1);
    int ylo = max(0, (int)floorf(miny) - 1);
    int yhi = min(IMG_H - 1, (int)floorf(maxy) + 1);
    if (xlo > xhi || ylo > yhi) return;

    int lx = lane & 7, lyn = lane >> 3;
    unsigned long long* kb = keybuf + (size_t)b * IMG_H * IMG_W;

    for (int y0 = ylo; y0 <= yhi; y0 += 8) {
        int y = y0 + lyn;
        bool yok = (y <= yhi);
        float py = (float)y + 0.5f;
        float pyd0 = py - v1.y, pyd1 = py - v2.y, pyd2 = py - v0.y;
        for (int x0 = xlo; x0 <= xhi; x0 += 8) {
            int x = x0 + lx;
            bool ok = yok && (x <= xhi);
            float px = (float)x + 0.5f;
            float e0 = dx0 * pyd0 - dy0 * (px - v1.x);
            float e1 = dx1 * pyd1 - dy1 * (px - v2.x);
            float e2 = dx2 * pyd2 - dy2 * (px - v0.x);
            float area = (e0 + e1) + e2;
            bool okA = fabsf(area) > 1e-9f;
            float s = (area > 0.0f) ? 1.0f : ((area < 0.0f) ? -1.0f : area);
            bool inside = (e0 * s >= 0.0f) && (e1 * s >= 0.0f) && (e2 * s >= 0.0f)
                          && okA && ok;
            if (__ballot(inside)) {
                float den = okA ? area : 1.0f;
                float zpix = ((e0 * z0 + e1 * z1) + e2 * z2) / den;
                if (inside && (zpix >= -1.0f) && (zpix <= 1.0f)) {
                    unsigned long long* ap = &kb[(size_t)y * IMG_W + x];
                    unsigned long long cur = *(const volatile unsigned long long*)ap;
                    unsigned long long k = packKey(zpix, f);
                    if (k < cur) atomicMin(ap, k);
                }
            }
        }
    }
}

// ---------------- shade + bilinear texture sample ----------------
__global__ void k_shade(const unsigned long long* __restrict__ keybuf,
                        const int* __restrict__ faces, const float4* __restrict__ vscr,
                        const float* __restrict__ uvmap, const float* __restrict__ tex,
                        float* __restrict__ out, int B, int N, int tside) {
#pragma clang fp contract(off)
    int id = blockIdx.x * blockDim.x + threadIdx.x;
    if (id >= B * IMG_H * IMG_W) return;
    int b = id / (IMG_H * IMG_W);
    int p = id - b * (IMG_H * IMG_W);
    int y = p / IMG_W, x = p - y * IMG_W;
    unsigned long long key = keybuf[id];
    int fid = (key == ~0ull) ? -1 : (int)(key & 0xFFFFFFFFull);
    int f = (fid < 0) ? 0 : fid;
    int i0 = faces[f * 3 + 0], i1 = faces[f * 3 + 1], i2 = faces[f * 3 + 2];
    float4 v0 = vscr[(size_t)b * N + i0];
    float4 v1 = vscr[(size_t)b * N + i1];
    float4 v2 = vscr[(size_t)b * N + i2];
    float px = (float)x + 0.5f, py = (float)y + 0.5f;
    float e0 = (v2.x - v1.x) * (py - v1.y) - (v2.y - v1.y) * (px - v1.x);
    float e1 = (v0.x - v2.x) * (py - v2.y) - (v0.y - v2.y) * (px - v2.x);
    float e2 = (v1.x - v0.x) * (py - v0.y) - (v1.y - v0.y) * (px - v0.x);
    float bw0 = e0 / v0.w, bw1 = e1 / v1.w, bw2 = e2 / v2.w;
    float den = (bw0 + bw1) + bw2;
    den = (fabsf(den) > 1e-9f) ? den : 1.0f;
    float pc0 = bw0 / den, pc1 = bw1 / den, pc2 = bw2 / den;
    float u0 = uvmap[((size_t)b * N + i0) * 2],     vv0 = uvmap[((size_t)b * N + i0) * 2 + 1];
    float u1 = uvmap[((size_t)b * N + i1) * 2],     vv1 = uvmap[((size_t)b * N + i1) * 2 + 1];
    float u2 = uvmap[((size_t)b * N + i2) * 2],     vv2 = uvmap[((size_t)b * N + i2) * 2 + 1];
    float g0 = (pc0 * 1.0f + pc1 * 1.0f) + pc2 * 1.0f;
    float g1 = (pc0 * u0 + pc1 * u1) + pc2 * u2;
    float g2 = (pc0 * vv0 + pc1 * vv1) + pc2 * vv2;
    float mask = (fid >= 0) ? 1.0f : 0.0f;
    g0 = g0 * mask; g1 = g1 * mask; g2 = g2 * mask;
    float ts = (float)tside;
    float iyf = fminf(fmaxf(g2, 0.0f), 1.0f) * ts;
    float ixf = fminf(fmaxf(g1, 0.0f), 1.0f) * ts;
    float fly = floorf(iyf), flx = floorf(ixf);
    float fy = iyf - fly, fx = ixf - flx;
    int iy = (int)fly, ix = (int)flx;
    int tmax = tside - 1;
    int iy0 = min(max(iy, 0), tmax),     iy1 = min(max(iy + 1, 0), tmax);
    int ix0 = min(max(ix, 0), tmax),     ix1 = min(max(ix + 1, 0), tmax);
    const float* tb = tex + (size_t)b * tside * tside * 3;
    const float* tl = tb + ((size_t)iy0 * tside + ix0) * 3;
    const float* tr = tb + ((size_t)iy0 * tside + ix1) * 3;
    const float* bl = tb + ((size_t)iy1 * tside + ix0) * 3;
    const float* br = tb + ((size_t)iy1 * tside + ix1) * 3;
    float omfx = 1.0f - fx, omfy = 1.0f - fy;
    float* o = out + (size_t)id * 3;
    for (int c = 0; c < 3; ++c) {
        float r = (((tl[c] * omfx) * omfy) + ((tr[c] * fx) * omfy)) + ((bl[c] * omfx) * fy);
        r = r + ((br[c] * fx) * fy);
        o[c] = r * g0;
    }
}

extern "C" void kernel_launch(void* const* d_in, const int* in_sizes, int n_in,
                              void* d_out, int out_size, void* d_ws, size_t ws_size,
                              hipStream_t stream) {
    const float* verts = (const float*)d_in[0];
    const float* uvmap = (const float*)d_in[1];
    const int*   faces = (const int*)d_in[2];
    const float* tex   = (const float*)d_in[3];
    const float* poses = (const float*)d_in[4];
    int B = in_sizes[4] / 16;
    int N = in_sizes[0] / (B * 3);
    int F = in_sizes[2] / 3;
    int texels = in_sizes[3] / (B * 3);
    int tside = (int)(sqrt((double)texels) + 0.5);

    char* ws = (char*)d_ws;
    size_t off = 0;
    float4* vscr = (float4*)(ws + off); off += (size_t)B * N * sizeof(float4);
    float4* rec  = (float4*)(ws + off); off += (size_t)B * F * 3 * sizeof(float4);
    unsigned long long* keybuf = (unsigned long long*)(ws + off);
    size_t keybytes = (size_t)B * IMG_H * IMG_W * sizeof(unsigned long long);
    off += keybytes;
    int cap = (F + NSUB - 1) / NSUB;
    int* list = (int*)(ws + off); off += (size_t)B * NTILES * NSUB * cap * sizeof(int);
    int* cnt  = (int*)(ws + off); off += (size_t)B * NTILES * NSUB * sizeof(int);

    if (ws_size >= off) {
        // binned path
        hipMemsetAsync(keybuf, 0xFF, keybytes, stream);
        hipMemsetAsync(cnt, 0, (size_t)B * NTILES * NSUB * sizeof(int), stream);
        k_vertex<<<(B * N + 255) / 256, 256, 0, stream>>>(verts, poses, vscr, B, N);
        k_bin<<<(B * F + 255) / 256, 256, 0, stream>>>(faces, vscr, rec, list, cnt, B, N, F);
        k_rasterBins<<<B * NTILES * NSUB, 256, 0, stream>>>(list, cnt, rec, keybuf, B, F);
        k_shade<<<(B * IMG_H * IMG_W + 255) / 256, 256, 0, stream>>>(
            keybuf, faces, vscr, uvmap, tex, (float*)d_out, B, N, tside);
    } else {
        // fallback: prior verified single-kernel raster (vscr + keybuf only)
        float4* vscr0 = (float4*)ws;
        unsigned long long* keybuf0 = (unsigned long long*)(ws + (size_t)B * N * sizeof(float4));
        hipMemsetAsync(keybuf0, 0xFF, keybytes, stream);
        k_vertex<<<(B * N + 255) / 256, 256, 0, stream>>>(verts, poses, vscr0, B, N);
        int nwaves = B * F;
        k_rasterF<<<(nwaves + 3) / 4, 256, 0, stream>>>(faces, vscr0, keybuf0, B, N, F);
        k_shade<<<(B * IMG_H * IMG_W + 255) / 256, 256, 0, stream>>>(
            keybuf0, faces, vscr0, uvmap, tex, (float*)d_out, B, N, tside);
    }
}

// Round 3
// 402.374 us; speedup vs baseline: 1.5763x; 1.5763x over previous
//
#include <hip/hip_runtime.h>
#include <cstdint>
#include <cmath>

#define IMG_H 128
#define IMG_W 128
#define TILE 16
#define TILES_X (IMG_W / TILE)      // 8
#define TILES_Y (IMG_H / TILE)      // 8
#define NTILES (TILES_X * TILES_Y)  // 64
#define NSUB 8                      // sub-lists per bin (binning atomic contention split)
#define CCH 128                     // faces per raster chunk-block (load-balance quantum)

// PROJ constants: computed in double exactly as the Python reference, then cast to f32.
constexpr double FOCAL_D = 140.0, NEAR_D = 0.1, FAR_D = 10.0;
constexpr double RIGHT_D = (IMG_W - 1.0) / 2.0 * NEAR_D / FOCAL_D;
constexpr double TOP_D   = RIGHT_D * ((double)IMG_H / (double)IMG_W);
constexpr float P00 = (float)(NEAR_D / RIGHT_D);
constexpr float P11 = (float)(NEAR_D / TOP_D);
constexpr float P22 = (float)(-(FAR_D + NEAR_D) / (FAR_D - NEAR_D));
constexpr float P32 = (float)(-2.0 * FAR_D * NEAR_D / (FAR_D - NEAR_D));

__device__ __forceinline__ unsigned long long packKey(float z, int f) {
    unsigned int zb = __float_as_uint(z);
    zb = (zb & 0x80000000u) ? ~zb : (zb | 0x80000000u);  // monotone total order
    return ((unsigned long long)zb << 32) | (unsigned int)f;
}

// ---------------- vertex transform: world -> screen (sx, sy, sz, w); also zeroes cnt ----------------
__global__ void k_vertex(const float* __restrict__ verts, const float* __restrict__ poses,
                         float4* __restrict__ vscr, int* __restrict__ cnt, int cntN,
                         int B, int N) {
#pragma clang fp contract(off)
    int id = blockIdx.x * blockDim.x + threadIdx.x;
    if (cnt && id < cntN) cnt[id] = 0;   // fused cnt init (cntN << B*N)
    if (id >= B * N) return;
    int b = id / N;
    const float* v = verts + (size_t)id * 3;
    const float* P = poses + (size_t)b * 16;
    float x = v[0], y = v[1], z = v[2];
    float cp[4][4] = {
        { P[0],  P[1],  P[2],  P[3]  },
        {-P[4], -P[5], -P[6], -P[7]  },
        {-P[8], -P[9], -P[10],-P[11] },
        { P[12], P[13], P[14], P[15] }
    };
    float cam[4];
    for (int j = 0; j < 4; ++j)
        cam[j] = ((x * cp[j][0] + y * cp[j][1]) + z * cp[j][2]) + cp[j][3];
    float c0 = cam[0] * P00;
    float c1 = cam[1] * P11;
    float c2 = (cam[2] * P22) + (cam[3] * P32);
    float c3 = cam[2] * (-1.0f);
    float sx = ((c0 / c3) * 0.5f + 0.5f) * (float)IMG_W;
    float sy = (0.5f - (c1 / c3) * 0.5f) * (float)IMG_H;
    float sz = c2 / c3;
    vscr[id] = make_float4(sx, sy, sz, c3);
}

// ---------------- phase 1: bin faces into 16x16-px tiles; build SoA face records; init keybuf ------
// recA = (x1, y1, x2, y2)        anchors for e0 (v1) and e1 (v2)
// recB = (x0, y0, miny, maxy)    anchor for e2 (v0) + clamped y-bbox for wave strip reject
// recC = (z0, z1, z2, 0)
// recD = (dx0, dy0, dx1, dy1)    edge deltas (bit-exact same f32 subs as reference)
__global__ void k_bin(const int* __restrict__ faces, const float4* __restrict__ vscr,
                      float4* __restrict__ recA, float4* __restrict__ recB,
                      float4* __restrict__ recC, float4* __restrict__ recD,
                      int* __restrict__ list, int* __restrict__ cnt,
                      unsigned long long* __restrict__ keybuf,
                      int B, int N, int F) {
#pragma clang fp contract(off)
    int id = blockIdx.x * blockDim.x + threadIdx.x;
    // fused keybuf init (B*IMG_H*IMG_W entries, grid has B*F threads)
    for (int i = id; i < B * IMG_H * IMG_W; i += B * F) keybuf[i] = ~0ull;
    if (id >= B * F) return;
    int b = id / F, f = id - b * F;
    int i0 = faces[f * 3 + 0], i1 = faces[f * 3 + 1], i2 = faces[f * 3 + 2];
    float4 v0 = vscr[(size_t)b * N + i0];
    float4 v1 = vscr[(size_t)b * N + i1];
    float4 v2 = vscr[(size_t)b * N + i2];

    // reference: ok=false if any w <= 1e-6 -> face contributes nothing
    if (!(v0.w > 1e-6f && v1.w > 1e-6f && v2.w > 1e-6f)) return;

    float minx = fminf(v0.x, fminf(v1.x, v2.x));
    float maxx = fmaxf(v0.x, fmaxf(v1.x, v2.x));
    float miny = fminf(v0.y, fminf(v1.y, v2.y));
    float maxy = fmaxf(v0.y, fmaxf(v1.y, v2.y));
    // NaN guard (reference: NaN edge fns -> inside false everywhere)
    if (!(minx <= maxx) || !(miny <= maxy)) return;
    // clamp to sane range before int conversion (huge coords from tiny w)
    minx = fmaxf(minx, -4.0f);  maxx = fminf(maxx, (float)IMG_W + 4.0f);
    miny = fmaxf(miny, -4.0f);  maxy = fminf(maxy, (float)IMG_H + 4.0f);
    // pixel index range with >=1px guard band for edge-fn rounding slack (verified)
    int xlo = max(0, (int)floorf(minx) - 1);
    int xhi = min(IMG_W - 1, (int)floorf(maxx) + 1);
    int ylo = max(0, (int)floorf(miny) - 1);
    int yhi = min(IMG_H - 1, (int)floorf(maxy) + 1);
    if (xlo > xhi || ylo > yhi) return;

    // SoA face records (coalesced stores)
    size_t r = (size_t)id;
    recA[r] = make_float4(v1.x, v1.y, v2.x, v2.y);
    recB[r] = make_float4(v0.x, v0.y, miny, maxy);
    recC[r] = make_float4(v0.z, v1.z, v2.z, 0.0f);
    recD[r] = make_float4(v2.x - v1.x, v2.y - v1.y, v0.x - v2.x, v0.y - v2.y);

    int tx0 = xlo >> 4, tx1 = xhi >> 4, ty0 = ylo >> 4, ty1 = yhi >> 4;
    int sub = f & (NSUB - 1);
    int cap = (F + NSUB - 1) / NSUB;   // faces with f%NSUB==sub per batch <= cap -> no overflow
    for (int ty = ty0; ty <= ty1; ++ty)
        for (int tx = tx0; tx <= tx1; ++tx) {
            int bin = b * NTILES + ty * TILES_X + tx;
            int slot = atomicAdd(&cnt[bin * NSUB + sub], 1);
            list[((size_t)bin * NSUB + sub) * cap + slot] = f;
        }
}

// ---------------- phase 2: one block per (bin, sub, chunk); register z-buffer ----------------
// Load-balance fix: fixed CCH-face work quantum per block -> no center-tile serial tail.
__global__ __launch_bounds__(256) void k_rasterChunk(const int* __restrict__ list,
        const int* __restrict__ cnt,
        const float4* __restrict__ recA, const float4* __restrict__ recB,
        const float4* __restrict__ recC, const float4* __restrict__ recD,
        unsigned long long* __restrict__ keybuf, int B, int F, int cap) {
#pragma clang fp contract(off)
    int ls = blockIdx.x;                 // bin*NSUB + sub
    int n = cnt[ls];
    int base = blockIdx.y * CCH;         // chunk offset in this sub-list
    if (base >= n) return;
    int m = min(CCH, n - base);
    int bin = ls >> 3;                   // NSUB == 8
    int b = bin / NTILES;
    int tile = bin - b * NTILES;
    const int* mylist = list + (size_t)ls * cap + base;

    int tx = tile & (TILES_X - 1), ty = tile >> 3;
    int t = threadIdx.x;
    int x = (tx << 4) + (t & 15);
    int y = (ty << 4) + (t >> 4);
    float px = (float)x + 0.5f, py = (float)y + 0.5f;
    // wave-uniform y-strip bounds: each wave covers 4 consecutive rows of the tile
    int wv = t >> 6;
    float strip_py0 = (float)((ty << 4) + (wv << 2)) + 0.5f;
    float strip_py1 = strip_py0 + 3.0f;

    unsigned long long key = ~0ull;

    __shared__ float4 sA[CCH], sB[CCH], sC[CCH], sD[CCH];
    __shared__ int sfid[CCH];

    if (t < m) {
        int f = mylist[t];
        sfid[t] = f;
        size_t r = (size_t)b * F + f;
        sA[t] = recA[r]; sB[t] = recB[r]; sC[t] = recC[r]; sD[t] = recD[r];
    }
    __syncthreads();

    for (int j = 0; j < m; ++j) {
        float4 bb = sB[j];
        // conservative wave-uniform y reject (clamped bbox; guard consistent with binning's +-1 px)
        if (bb.z - 1.5f > strip_py1 || bb.w + 1.5f < strip_py0) continue;
        float4 aa = sA[j], cc = sC[j], dd = sD[j];
        // bit-exact reference op order (contract off):
        //   e = (dx)*(py - ay) - (dy)*(px - ax), deltas precomputed with identical f32 subs
        float e0 = dd.x * (py - aa.y) - dd.y * (px - aa.x);
        float e1 = dd.z * (py - aa.w) - dd.w * (px - aa.z);
        float dx2 = aa.x - bb.x, dy2 = aa.y - bb.y;       // v1 - v0 (same as reference)
        float e2 = dx2 * (py - bb.y) - dy2 * (px - bb.x);
        float area = (e0 + e1) + e2;
        bool okA = fabsf(area) > 1e-9f;
        float s = (area > 0.0f) ? 1.0f : ((area < 0.0f) ? -1.0f : area);
        bool inside = (e0 * s >= 0.0f) && (e1 * s >= 0.0f) && (e2 * s >= 0.0f) && okA;
        if (__ballot(inside)) {
            float den = okA ? area : 1.0f;
            float zpix = ((e0 * cc.x + e1 * cc.y) + e2 * cc.z) / den;
            if (inside && (zpix >= -1.0f) && (zpix <= 1.0f)) {
                unsigned long long k = packKey(zpix, sfid[j]);
                key = (k < key) ? k : key;    // register z-buffer: no global traffic
            }
        }
    }
    if (key != ~0ull) {
        unsigned long long* ap = &keybuf[(size_t)b * (IMG_H * IMG_W) + (size_t)y * IMG_W + x];
        atomicMin(ap, key);                  // <= (chunks covering tile) atomics per pixel
    }
}

// ---------------- fallback rasterizer (prior verified kernel) if workspace too small ----------------
__global__ __launch_bounds__(256) void k_rasterF(const int* __restrict__ faces,
                                                 const float4* __restrict__ vscr,
                                                 unsigned long long* __restrict__ keybuf,
                                                 int B, int N, int F) {
#pragma clang fp contract(off)
    int wid = __builtin_amdgcn_readfirstlane(blockIdx.x * 4 + (threadIdx.x >> 6));
    if (wid >= B * F) return;
    int b = wid / F;
    int f = wid - b * F;
    int lane = threadIdx.x & 63;

    int i0 = faces[f * 3 + 0], i1 = faces[f * 3 + 1], i2 = faces[f * 3 + 2];
    float4 v0 = vscr[(size_t)b * N + i0];
    float4 v1 = vscr[(size_t)b * N + i1];
    float4 v2 = vscr[(size_t)b * N + i2];
    if (!(v0.w > 1e-6f && v1.w > 1e-6f && v2.w > 1e-6f)) return;

    float dx0 = v2.x - v1.x, dy0 = v2.y - v1.y;
    float dx1 = v0.x - v2.x, dy1 = v0.y - v2.y;
    float dx2 = v1.x - v0.x, dy2 = v1.y - v0.y;
    float z0 = v0.z, z1 = v1.z, z2 = v2.z;

    float minx = fminf(v0.x, fminf(v1.x, v2.x));
    float maxx = fmaxf(v0.x, fmaxf(v1.x, v2.x));
    float miny = fminf(v0.y, fminf(v1.y, v2.y));
    float maxy = fmaxf(v0.y, fmaxf(v1.y, v2.y));
    if (!(minx <= maxx) || !(miny <= maxy)) return;
    minx = fmaxf(minx, -4.0f);  maxx = fminf(maxx, (float)IMG_W + 4.0f);
    miny = fmaxf(miny, -4.0f);  maxy = fminf(maxy, (float)IMG_H + 4.0f);
    int xlo = max(0, (int)floorf(minx) - 1);
    int xhi = min(IMG_W - 1, (int)floorf(maxx) + 1);
    int ylo = max(0, (int)floorf(miny) - 1);
    int yhi = min(IMG_H - 1, (int)floorf(maxy) + 1);
    if (xlo > xhi || ylo > yhi) return;

    int lx = lane & 7, lyn = lane >> 3;
    unsigned long long* kb = keybuf + (size_t)b * IMG_H * IMG_W;

    for (int y0 = ylo; y0 <= yhi; y0 += 8) {
        int y = y0 + lyn;
        bool yok = (y <= yhi);
        float py = (float)y + 0.5f;
        float pyd0 = py - v1.y, pyd1 = py - v2.y, pyd2 = py - v0.y;
        for (int x0 = xlo; x0 <= xhi; x0 += 8) {
            int x = x0 + lx;
            bool ok = yok && (x <= xhi);
            float px = (float)x + 0.5f;
            float e0 = dx0 * pyd0 - dy0 * (px - v1.x);
            float e1 = dx1 * pyd1 - dy1 * (px - v2.x);
            float e2 = dx2 * pyd2 - dy2 * (px - v0.x);
            float area = (e0 + e1) + e2;
            bool okA = fabsf(area) > 1e-9f;
            float s = (area > 0.0f) ? 1.0f : ((area < 0.0f) ? -1.0f : area);
            bool inside = (e0 * s >= 0.0f) && (e1 * s >= 0.0f) && (e2 * s >= 0.0f)
                          && okA && ok;
            if (__ballot(inside)) {
                float den = okA ? area : 1.0f;
                float zpix = ((e0 * z0 + e1 * z1) + e2 * z2) / den;
                if (inside && (zpix >= -1.0f) && (zpix <= 1.0f)) {
                    unsigned long long* ap = &kb[(size_t)y * IMG_W + x];
                    unsigned long long cur = *(const volatile unsigned long long*)ap;
                    unsigned long long k = packKey(zpix, f);
                    if (k < cur) atomicMin(ap, k);
                }
            }
        }
    }
}

// ---------------- shade + bilinear texture sample ----------------
__global__ void k_shade(const unsigned long long* __restrict__ keybuf,
                        const int* __restrict__ faces, const float4* __restrict__ vscr,
                        const float* __restrict__ uvmap, const float* __restrict__ tex,
                        float* __restrict__ out, int B, int N, int tside) {
#pragma clang fp contract(off)
    int id = blockIdx.x * blockDim.x + threadIdx.x;
    if (id >= B * IMG_H * IMG_W) return;
    int b = id / (IMG_H * IMG_W);
    int p = id - b * (IMG_H * IMG_W);
    int y = p / IMG_W, x = p - y * IMG_W;
    unsigned long long key = keybuf[id];
    int fid = (key == ~0ull) ? -1 : (int)(key & 0xFFFFFFFFull);
    int f = (fid < 0) ? 0 : fid;
    int i0 = faces[f * 3 + 0], i1 = faces[f * 3 + 1], i2 = faces[f * 3 + 2];
    float4 v0 = vscr[(size_t)b * N + i0];
    float4 v1 = vscr[(size_t)b * N + i1];
    float4 v2 = vscr[(size_t)b * N + i2];
    float px = (float)x + 0.5f, py = (float)y + 0.5f;
    float e0 = (v2.x - v1.x) * (py - v1.y) - (v2.y - v1.y) * (px - v1.x);
    float e1 = (v0.x - v2.x) * (py - v2.y) - (v0.y - v2.y) * (px - v2.x);
    float e2 = (v1.x - v0.x) * (py - v0.y) - (v1.y - v0.y) * (px - v0.x);
    float bw0 = e0 / v0.w, bw1 = e1 / v1.w, bw2 = e2 / v2.w;
    float den = (bw0 + bw1) + bw2;
    den = (fabsf(den) > 1e-9f) ? den : 1.0f;
    float pc0 = bw0 / den, pc1 = bw1 / den, pc2 = bw2 / den;
    float u0 = uvmap[((size_t)b * N + i0) * 2],     vv0 = uvmap[((size_t)b * N + i0) * 2 + 1];
    float u1 = uvmap[((size_t)b * N + i1) * 2],     vv1 = uvmap[((size_t)b * N + i1) * 2 + 1];
    float u2 = uvmap[((size_t)b * N + i2) * 2],     vv2 = uvmap[((size_t)b * N + i2) * 2 + 1];
    float g0 = (pc0 * 1.0f + pc1 * 1.0f) + pc2 * 1.0f;
    float g1 = (pc0 * u0 + pc1 * u1) + pc2 * u2;
    float g2 = (pc0 * vv0 + pc1 * vv1) + pc2 * vv2;
    float mask = (fid >= 0) ? 1.0f : 0.0f;
    g0 = g0 * mask; g1 = g1 * mask; g2 = g2 * mask;
    float ts = (float)tside;
    float iyf = fminf(fmaxf(g2, 0.0f), 1.0f) * ts;
    float ixf = fminf(fmaxf(g1, 0.0f), 1.0f) * ts;
    float fly = floorf(iyf), flx = floorf(ixf);
    float fy = iyf - fly, fx = ixf - flx;
    int iy = (int)fly, ix = (int)flx;
    int tmax = tside - 1;
    int iy0 = min(max(iy, 0), tmax),     iy1 = min(max(iy + 1, 0), tmax);
    int ix0 = min(max(ix, 0), tmax),     ix1 = min(max(ix + 1, 0), tmax);
    const float* tb = tex + (size_t)b * tside * tside * 3;
    const float* tl = tb + ((size_t)iy0 * tside + ix0) * 3;
    const float* tr = tb + ((size_t)iy0 * tside + ix1) * 3;
    const float* bl = tb + ((size_t)iy1 * tside + ix0) * 3;
    const float* br = tb + ((size_t)iy1 * tside + ix1) * 3;
    float omfx = 1.0f - fx, omfy = 1.0f - fy;
    float* o = out + (size_t)id * 3;
    for (int c = 0; c < 3; ++c) {
        float r = (((tl[c] * omfx) * omfy) + ((tr[c] * fx) * omfy)) + ((bl[c] * omfx) * fy);
        r = r + ((br[c] * fx) * fy);
        o[c] = r * g0;
    }
}

extern "C" void kernel_launch(void* const* d_in, const int* in_sizes, int n_in,
                              void* d_out, int out_size, void* d_ws, size_t ws_size,
                              hipStream_t stream) {
    const float* verts = (const float*)d_in[0];
    const float* uvmap = (const float*)d_in[1];
    const int*   faces = (const int*)d_in[2];
    const float* tex   = (const float*)d_in[3];
    const float* poses = (const float*)d_in[4];
    int B = in_sizes[4] / 16;
    int N = in_sizes[0] / (B * 3);
    int F = in_sizes[2] / 3;
    int texels = in_sizes[3] / (B * 3);
    int tside = (int)(sqrt((double)texels) + 0.5);

    char* ws = (char*)d_ws;
    size_t off = 0;
    float4* vscr = (float4*)(ws + off); off += (size_t)B * N * sizeof(float4);
    float4* recA = (float4*)(ws + off); off += (size_t)B * F * sizeof(float4);
    float4* recB = (float4*)(ws + off); off += (size_t)B * F * sizeof(float4);
    float4* recC = (float4*)(ws + off); off += (size_t)B * F * sizeof(float4);
    float4* recD = (float4*)(ws + off); off += (size_t)B * F * sizeof(float4);
    unsigned long long* keybuf = (unsigned long long*)(ws + off);
    size_t keybytes = (size_t)B * IMG_H * IMG_W * sizeof(unsigned long long);
    off += keybytes;
    int cap = (F + NSUB - 1) / NSUB;
    int* list = (int*)(ws + off); off += (size_t)B * NTILES * NSUB * cap * sizeof(int);
    int* cnt  = (int*)(ws + off); off += (size_t)B * NTILES * NSUB * sizeof(int);
    int cntN = B * NTILES * NSUB;

    if (ws_size >= off) {
        // binned + chunked path (no memsets: inits fused into k_vertex / k_bin)
        k_vertex<<<(B * N + 255) / 256, 256, 0, stream>>>(verts, poses, vscr, cnt, cntN, B, N);
        k_bin<<<(B * F + 255) / 256, 256, 0, stream>>>(faces, vscr, recA, recB, recC, recD,
                                                       list, cnt, keybuf, B, N, F);
        int kmax = (cap + CCH - 1) / CCH;
        dim3 rgrid(B * NTILES * NSUB, kmax);
        k_rasterChunk<<<rgrid, 256, 0, stream>>>(list, cnt, recA, recB, recC, recD,
                                                 keybuf, B, F, cap);
        k_shade<<<(B * IMG_H * IMG_W + 255) / 256, 256, 0, stream>>>(
            keybuf, faces, vscr, uvmap, tex, (float*)d_out, B, N, tside);
    } else {
        // fallback: prior verified single-kernel raster (vscr + keybuf only)
        float4* vscr0 = (float4*)ws;
        unsigned long long* keybuf0 = (unsigned long long*)(ws + (size_t)B * N * sizeof(float4));
        hipMemsetAsync(keybuf0, 0xFF, keybytes, stream);
        k_vertex<<<(B * N + 255) / 256, 256, 0, stream>>>(verts, poses, vscr0, (int*)nullptr, 0, B, N);
        int nwaves = B * F;
        k_rasterF<<<(nwaves + 3) / 4, 256, 0, stream>>>(faces, vscr0, keybuf0, B, N, F);
        k_shade<<<(B * IMG_H * IMG_W + 255) / 256, 256, 0, stream>>>(
            keybuf0, faces, vscr0, uvmap, tex, (float*)d_out, B, N, tside);
    }
}

// Round 9
// 377.819 us; speedup vs baseline: 1.6788x; 1.0650x over previous
//
#include <hip/hip_runtime.h>
#include <cstdint>
#include <cmath>

#define IMG_H 128
#define IMG_W 128
#define TILE 16
#define TILES_X (IMG_W / TILE)      // 8
#define TILES_Y (IMG_H / TILE)      // 8
#define NTILES (TILES_X * TILES_Y)  // 64
#define NSUB 8                      // sub-lists per bin (binning atomic contention split)
#define CCH 128                     // faces per raster chunk-block (load-balance quantum)

// PROJ constants: computed in double exactly as the Python reference, then cast to f32.
constexpr double FOCAL_D = 140.0, NEAR_D = 0.1, FAR_D = 10.0;
constexpr double RIGHT_D = (IMG_W - 1.0) / 2.0 * NEAR_D / FOCAL_D;
constexpr double TOP_D   = RIGHT_D * ((double)IMG_H / (double)IMG_W);
constexpr float P00 = (float)(NEAR_D / RIGHT_D);
constexpr float P11 = (float)(NEAR_D / TOP_D);
constexpr float P22 = (float)(-(FAR_D + NEAR_D) / (FAR_D - NEAR_D));
constexpr float P32 = (float)(-2.0 * FAR_D * NEAR_D / (FAR_D - NEAR_D));

__device__ __forceinline__ unsigned long long packKey(float z, int f) {
    unsigned int zb = __float_as_uint(z);
    zb = (zb & 0x80000000u) ? ~zb : (zb | 0x80000000u);  // monotone total order
    return ((unsigned long long)zb << 32) | (unsigned int)f;
}

// Conservative "all 4 tile corners strictly outside this edge" test.
// Affine edge fn -> extremes at rect corners. Margin covers FP eval error
// (~few ulp of term magnitude). NaN anywhere -> comparisons false -> keep tile.
__device__ __forceinline__ bool edgeAllOut(float dx, float dy, float ax, float ay,
                                           float px0, float px1, float py0, float py1,
                                           float s) {
#pragma clang fp contract(off)
    bool all = true;
    #pragma unroll
    for (int c = 0; c < 4; ++c) {
        float px = (c & 1) ? px1 : px0;
        float py = (c & 2) ? py1 : py0;
        float e = dx * (py - ay) - dy * (px - ax);
        float T = fabsf(dx) * (fabsf(py) + fabsf(ay)) + fabsf(dy) * (fabsf(px) + fabsf(ax));
        float m = 1e-5f * T + 1e-3f;
        all = all && (e * s < -m);
    }
    return all;
}

// ---------------- vertex transform: world -> screen (sx, sy, sz, w); also zeroes cnt ----------------
__global__ void k_vertex(const float* __restrict__ verts, const float* __restrict__ poses,
                         float4* __restrict__ vscr, int* __restrict__ cnt, int cntN,
                         int B, int N) {
#pragma clang fp contract(off)
    int id = blockIdx.x * blockDim.x + threadIdx.x;
    if (cnt && id < cntN) cnt[id] = 0;   // fused cnt init (cntN << B*N)
    if (id >= B * N) return;
    int b = id / N;
    const float* v = verts + (size_t)id * 3;
    const float* P = poses + (size_t)b * 16;
    float x = v[0], y = v[1], z = v[2];
    float cp[4][4] = {
        { P[0],  P[1],  P[2],  P[3]  },
        {-P[4], -P[5], -P[6], -P[7]  },
        {-P[8], -P[9], -P[10],-P[11] },
        { P[12], P[13], P[14], P[15] }
    };
    float cam[4];
    for (int j = 0; j < 4; ++j)
        cam[j] = ((x * cp[j][0] + y * cp[j][1]) + z * cp[j][2]) + cp[j][3];
    float c0 = cam[0] * P00;
    float c1 = cam[1] * P11;
    float c2 = (cam[2] * P22) + (cam[3] * P32);
    float c3 = cam[2] * (-1.0f);
    float sx = ((c0 / c3) * 0.5f + 0.5f) * (float)IMG_W;
    float sy = (0.5f - (c1 / c3) * 0.5f) * (float)IMG_H;
    float sz = c2 / c3;
    vscr[id] = make_float4(sx, sy, sz, c3);
}

// ---------------- phase 1: bin faces with exact tile culling; SoA records; init keybuf ------
// recA = (x1, y1, x2, y2)                 anchors for e0 (v1) and e1 (v2)
// recB = (x0, y0, -, -)                   anchor for e2 (v0)
// recC = (z0, z1, z2, bits(packed bbox))  z + int pixel bbox packed 4x u8 (xlo,xhi,ylo,yhi)
// recD = (dx0, dy0, dx1, dy1)             edge deltas (bit-exact same f32 subs as reference)
__global__ void k_bin(const int* __restrict__ faces, const float4* __restrict__ vscr,
                      float4* __restrict__ recA, float4* __restrict__ recB,
                      float4* __restrict__ recC, float4* __restrict__ recD,
                      int* __restrict__ list, int* __restrict__ cnt,
                      unsigned long long* __restrict__ keybuf,
                      int B, int N, int F) {
#pragma clang fp contract(off)
    int id = blockIdx.x * blockDim.x + threadIdx.x;
    // fused keybuf init (B*IMG_H*IMG_W entries, grid has B*F threads)
    for (int i = id; i < B * IMG_H * IMG_W; i += B * F) keybuf[i] = ~0ull;
    if (id >= B * F) return;
    int b = id / F, f = id - b * F;
    int i0 = faces[f * 3 + 0], i1 = faces[f * 3 + 1], i2 = faces[f * 3 + 2];
    float4 v0 = vscr[(size_t)b * N + i0];
    float4 v1 = vscr[(size_t)b * N + i1];
    float4 v2 = vscr[(size_t)b * N + i2];

    // reference: ok=false if any w <= 1e-6 -> face contributes nothing
    if (!(v0.w > 1e-6f && v1.w > 1e-6f && v2.w > 1e-6f)) return;

    float minx = fminf(v0.x, fminf(v1.x, v2.x));
    float maxx = fmaxf(v0.x, fmaxf(v1.x, v2.x));
    float miny = fminf(v0.y, fminf(v1.y, v2.y));
    float maxy = fmaxf(v0.y, fmaxf(v1.y, v2.y));
    // NaN guard (reference: NaN edge fns -> inside false everywhere)
    if (!(minx <= maxx) || !(miny <= maxy)) return;
    // clamp to sane range before int conversion (huge coords from tiny w)
    minx = fmaxf(minx, -4.0f);  maxx = fminf(maxx, (float)IMG_W + 4.0f);
    miny = fmaxf(miny, -4.0f);  maxy = fminf(maxy, (float)IMG_H + 4.0f);
    // pixel index range with >=1px guard band for edge-fn rounding slack (verified)
    int xlo = max(0, (int)floorf(minx) - 1);
    int xhi = min(IMG_W - 1, (int)floorf(maxx) + 1);
    int ylo = max(0, (int)floorf(miny) - 1);
    int yhi = min(IMG_H - 1, (int)floorf(maxy) + 1);
    if (xlo > xhi || ylo > yhi) return;

    // edge deltas (identical f32 subs as reference/raster)
    float dx0 = v2.x - v1.x, dy0 = v2.y - v1.y;   // e0 anchor (v1)
    float dx1 = v0.x - v2.x, dy1 = v0.y - v2.y;   // e1 anchor (v2)
    float dx2 = v1.x - v0.x, dy2 = v1.y - v0.y;   // e2 anchor (v0)

    // SoA face records (coalesced stores)
    size_t r = (size_t)id;
    unsigned pb = (unsigned)xlo | ((unsigned)xhi << 8) | ((unsigned)ylo << 16) | ((unsigned)yhi << 24);
    recA[r] = make_float4(v1.x, v1.y, v2.x, v2.y);
    recB[r] = make_float4(v0.x, v0.y, 0.0f, 0.0f);
    recC[r] = make_float4(v0.z, v1.z, v2.z, __uint_as_float(pb));
    recD[r] = make_float4(dx0, dy0, dx1, dy1);

    int tx0 = xlo >> 4, tx1 = xhi >> 4, ty0 = ylo >> 4, ty1 = yhi >> 4;
    int sub = f & (NSUB - 1);
    int cap = (F + NSUB - 1) / NSUB;   // faces with f%NSUB==sub per batch <= cap -> no overflow
    for (int ty = ty0; ty <= ty1; ++ty) {
        float py0 = (float)(ty << 4) + 0.5f, py1 = py0 + 15.0f;
        for (int tx = tx0; tx <= tx1; ++tx) {
            float px0 = (float)(tx << 4) + 0.5f, px1 = px0 + 15.0f;
            // exact conservative tile cull: area sign at corner 0 (with margin), then
            // "all corners outside one edge" -> no pixel center in tile can be inside.
            float ea = dx0 * (py0 - v1.y) - dy0 * (px0 - v1.x);
            float eb = dx1 * (py0 - v2.y) - dy1 * (px0 - v2.x);
            float ec = dx2 * (py0 - v0.y) - dy2 * (px0 - v0.x);
            float areaC = (ea + eb) + ec;
            float Tm = (fabsf(dx0) + fabsf(dx1) + fabsf(dx2)) * 300.0f
                     + (fabsf(dy0) + fabsf(dy1) + fabsf(dy2)) * 300.0f;
            float mA = 1e-5f * Tm + 1e-2f;
            bool cull = false;
            if (fabsf(areaC) > mA) {   // sign stable over tile -> culling valid
                float s = (areaC > 0.0f) ? 1.0f : -1.0f;
                cull = edgeAllOut(dx0, dy0, v1.x, v1.y, px0, px1, py0, py1, s)
                    || edgeAllOut(dx1, dy1, v2.x, v2.y, px0, px1, py0, py1, s)
                    || edgeAllOut(dx2, dy2, v0.x, v0.y, px0, px1, py0, py1, s);
            }
            if (cull) continue;
            int bin = b * NTILES + ty * TILES_X + tx;
            int slot = atomicAdd(&cnt[bin * NSUB + sub], 1);
            list[((size_t)bin * NSUB + sub) * cap + slot] = f;
        }
    }
}

// ---------------- phase 2: one block per (bin, sub, chunk); register z-buffer ----------------
// Waves own 8x8 quadrants -> per-face wave reject in BOTH x and y via packed int bbox.
__global__ __launch_bounds__(256) void k_rasterChunk(const int* __restrict__ list,
        const int* __restrict__ cnt,
        const float4* __restrict__ recA, const float4* __restrict__ recB,
        const float4* __restrict__ recC, const float4* __restrict__ recD,
        unsigned long long* __restrict__ keybuf, int B, int F, int cap) {
#pragma clang fp contract(off)
    int ls = blockIdx.x;                 // bin*NSUB + sub
    int n = cnt[ls];
    int base = blockIdx.y * CCH;         // chunk offset in this sub-list
    if (base >= n) return;
    int m = min(CCH, n - base);
    int bin = ls >> 3;                   // NSUB == 8
    int b = bin / NTILES;
    int tile = bin - b * NTILES;
    const int* mylist = list + (size_t)ls * cap + base;

    int tx = tile & (TILES_X - 1), ty = tile >> 3;
    int t = threadIdx.x;
    int wv = t >> 6;                     // wave id 0..3 -> 8x8 quadrant (wv&1, wv>>1)
    int wx0 = (tx << 4) + ((wv & 1) << 3);
    int wy0 = (ty << 4) + ((wv >> 1) << 3);
    int x = wx0 + (t & 7);
    int y = wy0 + ((t >> 3) & 7);
    float px = (float)x + 0.5f, py = (float)y + 0.5f;
    int wx1 = wx0 + 7, wy1 = wy0 + 7;

    unsigned long long key = ~0ull;

    __shared__ float4 sA[CCH], sB[CCH], sC[CCH], sD[CCH];
    __shared__ int sfid[CCH];

    if (t < m) {
        int f = mylist[t];
        sfid[t] = f;
        size_t r = (size_t)b * F + f;
        sA[t] = recA[r]; sB[t] = recB[r]; sC[t] = recC[r]; sD[t] = recD[r];
    }
    __syncthreads();

    for (int j = 0; j < m; ++j) {
        float4 cc = sC[j];
        // wave-level bbox reject (x AND y, 8x8 quadrant, int bbox incl. +-1 guard)
        unsigned pb = __float_as_uint(cc.w);
        int fxlo = (int)(pb & 0xFFu), fxhi = (int)((pb >> 8) & 0xFFu);
        int fylo = (int)((pb >> 16) & 0xFFu), fyhi = (int)(pb >> 24);
        if (fxhi < wx0 || fxlo > wx1 || fyhi < wy0 || fylo > wy1) continue;
        float4 aa = sA[j], bb = sB[j], dd = sD[j];
        // bit-exact reference op order (contract off):
        float e0 = dd.x * (py - aa.y) - dd.y * (px - aa.x);
        float e1 = dd.z * (py - aa.w) - dd.w * (px - aa.z);
        float dx2 = aa.x - bb.x, dy2 = aa.y - bb.y;       // v1 - v0 (same as reference)
        float e2 = dx2 * (py - bb.y) - dy2 * (px - bb.x);
        float area = (e0 + e1) + e2;
        bool okA = fabsf(area) > 1e-9f;
        float s = (area > 0.0f) ? 1.0f : ((area < 0.0f) ? -1.0f : area);
        bool inside = (e0 * s >= 0.0f) && (e1 * s >= 0.0f) && (e2 * s >= 0.0f) && okA;
        if (__ballot(inside)) {
            float den = okA ? area : 1.0f;
            float zpix = ((e0 * cc.x + e1 * cc.y) + e2 * cc.z) / den;
            if (inside && (zpix >= -1.0f) && (zpix <= 1.0f)) {
                unsigned long long k = packKey(zpix, sfid[j]);
                key = (k < key) ? k : key;    // register z-buffer: no global traffic
            }
        }
    }
    if (key != ~0ull) {
        unsigned long long* ap = &keybuf[(size_t)b * (IMG_H * IMG_W) + (size_t)y * IMG_W + x];
        atomicMin(ap, key);                  // <= (chunks covering tile) atomics per pixel
    }
}

// ---------------- fallback rasterizer (prior verified kernel) if workspace too small ----------------
__global__ __launch_bounds__(256) void k_rasterF(const int* __restrict__ faces,
                                                 const float4* __restrict__ vscr,
                                                 unsigned long long* __restrict__ keybuf,
                                                 int B, int N, int F) {
#pragma clang fp contract(off)
    int wid = __builtin_amdgcn_readfirstlane(blockIdx.x * 4 + (threadIdx.x >> 6));
    if (wid >= B * F) return;
    int b = wid / F;
    int f = wid - b * F;
    int lane = threadIdx.x & 63;

    int i0 = faces[f * 3 + 0], i1 = faces[f * 3 + 1], i2 = faces[f * 3 + 2];
    float4 v0 = vscr[(size_t)b * N + i0];
    float4 v1 = vscr[(size_t)b * N + i1];
    float4 v2 = vscr[(size_t)b * N + i2];
    if (!(v0.w > 1e-6f && v1.w > 1e-6f && v2.w > 1e-6f)) return;

    float dx0 = v2.x - v1.x, dy0 = v2.y - v1.y;
    float dx1 = v0.x - v2.x, dy1 = v0.y - v2.y;
    float dx2 = v1.x - v0.x, dy2 = v1.y - v0.y;
    float z0 = v0.z, z1 = v1.z, z2 = v2.z;

    float minx = fminf(v0.x, fminf(v1.x, v2.x));
    float maxx = fmaxf(v0.x, fmaxf(v1.x, v2.x));
    float miny = fminf(v0.y, fminf(v1.y, v2.y));
    float maxy = fmaxf(v0.y, fmaxf(v1.y, v2.y));
    if (!(minx <= maxx) || !(miny <= maxy)) return;
    minx = fmaxf(minx, -4.0f);  maxx = fminf(maxx, (float)IMG_W + 4.0f);
    miny = fmaxf(miny, -4.0f);  maxy = fminf(maxy, (float)IMG_H + 4.0f);
    int xlo = max(0, (int)floorf(minx) - 1);
    int xhi = min(IMG_W - 1, (int)floorf(maxx) + 1);
    int ylo = max(0, (int)floorf(miny) - 1);
    int yhi = min(IMG_H - 1, (int)floorf(maxy) + 1);
    if (xlo > xhi || ylo > yhi) return;

    int lx = lane & 7, lyn = lane >> 3;
    unsigned long long* kb = keybuf + (size_t)b * IMG_H * IMG_W;

    for (int y0 = ylo; y0 <= yhi; y0 += 8) {
        int y = y0 + lyn;
        bool yok = (y <= yhi);
        float py = (float)y + 0.5f;
        float pyd0 = py - v1.y, pyd1 = py - v2.y, pyd2 = py - v0.y;
        for (int x0 = xlo; x0 <= xhi; x0 += 8) {
            int x = x0 + lx;
            bool ok = yok && (x <= xhi);
            float px = (float)x + 0.5f;
            float e0 = dx0 * pyd0 - dy0 * (px - v1.x);
            float e1 = dx1 * pyd1 - dy1 * (px - v2.x);
            float e2 = dx2 * pyd2 - dy2 * (px - v0.x);
            float area = (e0 + e1) + e2;
            bool okA = fabsf(area) > 1e-9f;
            float s = (area > 0.0f) ? 1.0f : ((area < 0.0f) ? -1.0f : area);
            bool inside = (e0 * s >= 0.0f) && (e1 * s >= 0.0f) && (e2 * s >= 0.0f)
                          && okA && ok;
            if (__ballot(inside)) {
                float den = okA ? area : 1.0f;
                float zpix = ((e0 * z0 + e1 * z1) + e2 * z2) / den;
                if (inside && (zpix >= -1.0f) && (zpix <= 1.0f)) {
                    unsigned long long* ap = &kb[(size_t)y * IMG_W + x];
                    unsigned long long cur = *(const volatile unsigned long long*)ap;
                    unsigned long long k = packKey(zpix, f);
                    if (k < cur) atomicMin(ap, k);
                }
            }
        }
    }
}

// ---------------- shade + bilinear texture sample ----------------
__global__ void k_shade(const unsigned long long* __restrict__ keybuf,
                        const int* __restrict__ faces, const float4* __restrict__ vscr,
                        const float* __restrict__ uvmap, const float* __restrict__ tex,
                        float* __restrict__ out, int B, int N, int tside) {
#pragma clang fp contract(off)
    int id = blockIdx.x * blockDim.x + threadIdx.x;
    if (id >= B * IMG_H * IMG_W) return;
    int b = id / (IMG_H * IMG_W);
    int p = id - b * (IMG_H * IMG_W);
    int y = p / IMG_W, x = p - y * IMG_W;
    unsigned long long key = keybuf[id];
    int fid = (key == ~0ull) ? -1 : (int)(key & 0xFFFFFFFFull);
    int f = (fid < 0) ? 0 : fid;
    int i0 = faces[f * 3 + 0], i1 = faces[f * 3 + 1], i2 = faces[f * 3 + 2];
    float4 v0 = vscr[(size_t)b * N + i0];
    float4 v1 = vscr[(size_t)b * N + i1];
    float4 v2 = vscr[(size_t)b * N + i2];
    float px = (float)x + 0.5f, py = (float)y + 0.5f;
    float e0 = (v2.x - v1.x) * (py - v1.y) - (v2.y - v1.y) * (px - v1.x);
    float e1 = (v0.x - v2.x) * (py - v2.y) - (v0.y - v2.y) * (px - v2.x);
    float e2 = (v1.x - v0.x) * (py - v0.y) - (v1.y - v0.y) * (px - v0.x);
    float bw0 = e0 / v0.w, bw1 = e1 / v1.w, bw2 = e2 / v2.w;
    float den = (bw0 + bw1) + bw2;
    den = (fabsf(den) > 1e-9f) ? den : 1.0f;
    float pc0 = bw0 / den, pc1 = bw1 / den, pc2 = bw2 / den;
    float u0 = uvmap[((size_t)b * N + i0) * 2],     vv0 = uvmap[((size_t)b * N + i0) * 2 + 1];
    float u1 = uvmap[((size_t)b * N + i1) * 2],     vv1 = uvmap[((size_t)b * N + i1) * 2 + 1];
    float u2 = uvmap[((size_t)b * N + i2) * 2],     vv2 = uvmap[((size_t)b * N + i2) * 2 + 1];
    float g0 = (pc0 * 1.0f + pc1 * 1.0f) + pc2 * 1.0f;
    float g1 = (pc0 * u0 + pc1 * u1) + pc2 * u2;
    float g2 = (pc0 * vv0 + pc1 * vv1) + pc2 * vv2;
    float mask = (fid >= 0) ? 1.0f : 0.0f;
    g0 = g0 * mask; g1 = g1 * mask; g2 = g2 * mask;
    float ts = (float)tside;
    float iyf = fminf(fmaxf(g2, 0.0f), 1.0f) * ts;
    float ixf = fminf(fmaxf(g1, 0.0f), 1.0f) * ts;
    float fly = floorf(iyf), flx = floorf(ixf);
    float fy = iyf - fly, fx = ixf - flx;
    int iy = (int)fly, ix = (int)flx;
    int tmax = tside - 1;
    int iy0 = min(max(iy, 0), tmax),     iy1 = min(max(iy + 1, 0), tmax);
    int ix0 = min(max(ix, 0), tmax),     ix1 = min(max(ix + 1, 0), tmax);
    const float* tb = tex + (size_t)b * tside * tside * 3;
    const float* tl = tb + ((size_t)iy0 * tside + ix0) * 3;
    const float* tr = tb + ((size_t)iy0 * tside + ix1) * 3;
    const float* bl = tb + ((size_t)iy1 * tside + ix0) * 3;
    const float* br = tb + ((size_t)iy1 * tside + ix1) * 3;
    float omfx = 1.0f - fx, omfy = 1.0f - fy;
    float* o = out + (size_t)id * 3;
    for (int c = 0; c < 3; ++c) {
        float r = (((tl[c] * omfx) * omfy) + ((tr[c] * fx) * omfy)) + ((bl[c] * omfx) * fy);
        r = r + ((br[c] * fx) * fy);
        o[c] = r * g0;
    }
}

extern "C" void kernel_launch(void* const* d_in, const int* in_sizes, int n_in,
                              void* d_out, int out_size, void* d_ws, size_t ws_size,
                              hipStream_t stream) {
    const float* verts = (const float*)d_in[0];
    const float* uvmap = (const float*)d_in[1];
    const int*   faces = (const int*)d_in[2];
    const float* tex   = (const float*)d_in[3];
    const float* poses = (const float*)d_in[4];
    int B = in_sizes[4] / 16;
    int N = in_sizes[0] / (B * 3);
    int F = in_sizes[2] / 3;
    int texels = in_sizes[3] / (B * 3);
    int tside = (int)(sqrt((double)texels) + 0.5);

    char* ws = (char*)d_ws;
    size_t off = 0;
    float4* vscr = (float4*)(ws + off); off += (size_t)B * N * sizeof(float4);
    float4* recA = (float4*)(ws + off); off += (size_t)B * F * sizeof(float4);
    float4* recB = (float4*)(ws + off); off += (size_t)B * F * sizeof(float4);
    float4* recC = (float4*)(ws + off); off += (size_t)B * F * sizeof(float4);
    float4* recD = (float4*)(ws + off); off += (size_t)B * F * sizeof(float4);
    unsigned long long* keybuf = (unsigned long long*)(ws + off);
    size_t keybytes = (size_t)B * IMG_H * IMG_W * sizeof(unsigned long long);
    off += keybytes;
    int cap = (F + NSUB - 1) / NSUB;
    int* list = (int*)(ws + off); off += (size_t)B * NTILES * NSUB * cap * sizeof(int);
    int* cnt  = (int*)(ws + off); off += (size_t)B * NTILES * NSUB * sizeof(int);
    int cntN = B * NTILES * NSUB;

    if (ws_size >= off) {
        // binned + chunked path (no memsets: inits fused into k_vertex / k_bin)
        k_vertex<<<(B * N + 255) / 256, 256, 0, stream>>>(verts, poses, vscr, cnt, cntN, B, N);
        k_bin<<<(B * F + 255) / 256, 256, 0, stream>>>(faces, vscr, recA, recB, recC, recD,
                                                       list, cnt, keybuf, B, N, F);
        int kmax = (cap + CCH - 1) / CCH;
        dim3 rgrid(B * NTILES * NSUB, kmax);
        k_rasterChunk<<<rgrid, 256, 0, stream>>>(list, cnt, recA, recB, recC, recD,
                                                 keybuf, B, F, cap);
        k_shade<<<(B * IMG_H * IMG_W + 255) / 256, 256, 0, stream>>>(
            keybuf, faces, vscr, uvmap, tex, (float*)d_out, B, N, tside);
    } else {
        // fallback: prior verified single-kernel raster (vscr + keybuf only)
        float4* vscr0 = (float4*)ws;
        unsigned long long* keybuf0 = (unsigned long long*)(ws + (size_t)B * N * sizeof(float4));
        hipMemsetAsync(keybuf0, 0xFF, keybytes, stream);
        k_vertex<<<(B * N + 255) / 256, 256, 0, stream>>>(verts, poses, vscr0, (int*)nullptr, 0, B, N);
        int nwaves = B * F;
        k_rasterF<<<(nwaves + 3) / 4, 256, 0, stream>>>(faces, vscr0, keybuf0, B, N, F);
        k_shade<<<(B * IMG_H * IMG_W + 255) / 256, 256, 0, stream>>>(
            keybuf0, faces, vscr0, uvmap, tex, (float*)d_out, B, N, tside);
    }
}